// Round 1
// baseline (71.142 us; speedup 1.0000x reference)
//
#include <hip/hip_runtime.h>

// ResNetVQC: 6 q3-layers of 32 three-qubit circuits + linear head.
// Each (layer,block,wire) expectation is an exact trilinear form:
//   z_w = sum_{p,q,r} T[p,q,r] * v0[p]*v1[q]*v2[r],  v = (1, cos x, sin x)
// T (6*32*3*27 floats) depends only on thetas -> built by a tiny setup kernel.

#define NBATCH 64
#define STRIDE 97

// ---------------- setup kernel: build T from thetas ----------------
// grid: 6 blocks (one per q3-layer), 256 threads: k = t>>3 (32 blocks), col = t&7 (8 basis columns)
__global__ __launch_bounds__(256) void build_T(const float* __restrict__ thetas,
                                               float* __restrict__ T) {
  __shared__ float Ur[32][8][8];  // [k][col][amp]
  __shared__ float Ui[32][8][8];
  const int l = blockIdx.x;
  const int t = threadIdx.x;
  const int k = t >> 3;
  const int col = t & 7;

  float pr[8], pi[8];
#pragma unroll
  for (int j = 0; j < 8; ++j) { pr[j] = (j == col) ? 1.f : 0.f; pi[j] = 0.f; }

  const float* th = thetas + (size_t)(l * 32 + k) * 54;  // [d][w][3]
#pragma unroll
  for (int d = 0; d < 6; ++d) {
#pragma unroll
    for (int w = 0; w < 3; ++w) {
      float phi = th[(d * 3 + w) * 3 + 0];
      float tht = th[(d * 3 + w) * 3 + 1];
      float omg = th[(d * 3 + w) * 3 + 2];
      float st, ct, sp, cp, sm, cm;
      __sincosf(0.5f * tht, &st, &ct);
      __sincosf(0.5f * (phi + omg), &sp, &cp);
      __sincosf(0.5f * (phi - omg), &sm, &cm);
      // Rot(phi,theta,omega): m00=e^{-i(phi+omg)/2}ct, m01=-e^{i(phi-omg)/2}st,
      //                       m10=e^{-i(phi-omg)/2}st, m11=e^{i(phi+omg)/2}ct
      float m00r =  cp * ct, m00i = -sp * ct;
      float m01r = -cm * st, m01i = -sm * st;
      float m10r =  cm * st, m10i = -sm * st;
      float m11r =  cp * ct, m11i =  sp * ct;
      const int s = 4 >> w;  // qubit0 = MSB (stride 4)
#pragma unroll
      for (int base = 0; base < 8; ++base) {
        if (base & s) continue;
        float ar = pr[base], ai = pi[base];
        float br = pr[base + s], bi = pi[base + s];
        pr[base]     = m00r * ar - m00i * ai + m01r * br - m01i * bi;
        pi[base]     = m00r * ai + m00i * ar + m01r * bi + m01i * br;
        pr[base + s] = m10r * ar - m10i * ai + m11r * br - m11i * bi;
        pi[base + s] = m10r * ai + m10i * ar + m11r * bi + m11i * br;
      }
    }
    const int r = (d & 1) + 1;  // CNOT ring range: 1,2,1,2,...
#pragma unroll
    for (int w = 0; w < 3; ++w) {
      const int cs = 4 >> w;
      const int ts = 4 >> ((w + r) % 3);
#pragma unroll
      for (int idx = 0; idx < 8; ++idx) {
        if (!(idx & cs) || (idx & ts)) continue;
        const int j2 = idx | ts;
        float tr = pr[idx]; pr[idx] = pr[j2]; pr[j2] = tr;
        float ti = pi[idx]; pi[idx] = pi[j2]; pi[j2] = ti;
      }
    }
  }
#pragma unroll
  for (int j = 0; j < 8; ++j) { Ur[k][col][j] = pr[j]; Ui[k][col][j] = pi[j]; }
  __syncthreads();

  if (col < 3) {
    const int w = col;  // wire
    // ReM[a][b] = sum_c zsign_w(c) * Re(conj(U[c][a]) U[c][b]);  U[c][a] = Ur[k][a][c]
    float rem[8][8];
#pragma unroll
    for (int a = 0; a < 8; ++a) {
#pragma unroll
      for (int bb = 0; bb < 8; ++bb) {
        float acc = 0.f;
#pragma unroll
        for (int c = 0; c < 8; ++c) {
          float zs = ((c >> (2 - w)) & 1) ? -1.f : 1.f;
          acc += zs * (Ur[k][a][c] * Ur[k][bb][c] + Ui[k][a][c] * Ui[k][bb][c]);
        }
        rem[a][bb] = acc;
      }
    }
    // basis change: a_i a_i' = sum_p Gp[i][i'] v_p,  v = (1, cos x, sin x)
    const int   ga[3][2] = {{0, 1}, {0, 1}, {0, 1}};
    const int   gb[3][2] = {{0, 1}, {0, 1}, {1, 0}};
    const float gc[3][2] = {{0.5f, 0.5f}, {0.5f, -0.5f}, {0.5f, 0.5f}};
    float* To = T + ((size_t)(l * 32 + k) * 3 + w) * 27;
#pragma unroll
    for (int p = 0; p < 3; ++p) {
#pragma unroll
      for (int q = 0; q < 3; ++q) {
#pragma unroll
        for (int rr = 0; rr < 3; ++rr) {
          float acc = 0.f;
#pragma unroll
          for (int e0 = 0; e0 < 2; ++e0)
#pragma unroll
            for (int e1 = 0; e1 < 2; ++e1)
#pragma unroll
              for (int e2 = 0; e2 < 2; ++e2) {
                int a  = (ga[p][e0] << 2) | (ga[q][e1] << 1) | ga[rr][e2];
                int bb = (gb[p][e0] << 2) | (gb[q][e1] << 1) | gb[rr][e2];
                acc += gc[p][e0] * gc[q][e1] * gc[rr][e2] * rem[a][bb];
              }
          To[p * 9 + q * 3 + rr] = acc;
        }
      }
    }
  }
}

// ---------------- main kernel ----------------
template <int NW>
__device__ __forceinline__ void q3eval(float x0, float x1, float x2,
                                       const float* __restrict__ tb,
                                       float* __restrict__ zz) {
  float s0, c0, s1, c1, s2, c2;
  __sincosf(x0, &s0, &c0);
  __sincosf(x1, &s1, &c1);
  __sincosf(x2, &s2, &c2);
  float m[27];
  m[0] = 1.f;      m[1] = c2;       m[2] = s2;
  m[3] = c1;       m[4] = c1 * c2;  m[5] = c1 * s2;
  m[6] = s1;       m[7] = s1 * c2;  m[8] = s1 * s2;
#pragma unroll
  for (int i = 0; i < 9; ++i) m[9 + i] = c0 * m[i];
#pragma unroll
  for (int i = 0; i < 9; ++i) m[18 + i] = s0 * m[i];
#pragma unroll
  for (int w = 0; w < NW; ++w) {
    float acc = tb[w * 27];  // m[0] == 1
#pragma unroll
    for (int i = 1; i < 27; ++i) acc = fmaf(tb[w * 27 + i], m[i], acc);
    zz[w] = acc;
  }
}

// block = 1024 threads = 16 waves; lane = batch elem (64/block), wave kw owns blocks {kw, kw+16}
__global__ __launch_bounds__(1024) void vqc_main(const float* __restrict__ x,
                                                 const float* __restrict__ T,
                                                 const float* __restrict__ wcls,
                                                 const float* __restrict__ bcls,
                                                 float* __restrict__ out) {
  __shared__ float buf[2][NBATCH][STRIDE];
  const int t = threadIdx.x;
  const int b0 = blockIdx.x * NBATCH;

  // stage x (coalesced) into buf[0]
#pragma unroll
  for (int i = 0; i < 6; ++i) {
    int idx = t + i * 1024;  // 0..6143 = 64*96
    buf[0][idx / 96][idx % 96] = x[(size_t)b0 * 96 + idx];
  }

  const int b = t & 63;                                    // batch within block
  const int ks = __builtin_amdgcn_readfirstlane(t >> 6);   // wave id 0..15 (scalar)

  // "fully" permutation gather indices: inp[3k+j] = H[3*((3k+j)%32) + (3k+j)/32]
  int gf[2][3];
#pragma unroll
  for (int kk = 0; kk < 2; ++kk) {
    int k = ks + 16 * kk;
#pragma unroll
    for (int j = 0; j < 3; ++j) {
      int m = 3 * k + j;
      gf[kk][j] = 3 * (m & 31) + (m >> 5);
    }
  }
  __syncthreads();

  float h[2][3];
  // layer 0 (stem): natural block order, no residual
#pragma unroll
  for (int kk = 0; kk < 2; ++kk) {
    int k = ks + 16 * kk;
    float z[3];
    q3eval<3>(buf[0][b][3 * k + 0], buf[0][b][3 * k + 1], buf[0][b][3 * k + 2],
              T + (size_t)k * 81, z);
    h[kk][0] = z[0]; h[kk][1] = z[1]; h[kk][2] = z[2];
    buf[1][b][3 * k + 0] = z[0];
    buf[1][b][3 * k + 1] = z[1];
    buf[1][b][3 * k + 2] = z[2];
  }
  __syncthreads();

  // layers 1..4: permuted input, residual add (own positions stay in regs)
  for (int l = 1; l < 5; ++l) {
    const float* Tl = T + (size_t)l * 32 * 81;
    const float* rdb = &buf[l & 1][0][0];
    float* wrb = &buf[(l & 1) ^ 1][0][0];
#pragma unroll
    for (int kk = 0; kk < 2; ++kk) {
      int k = ks + 16 * kk;
      float x0 = rdb[b * STRIDE + gf[kk][0]];
      float x1 = rdb[b * STRIDE + gf[kk][1]];
      float x2 = rdb[b * STRIDE + gf[kk][2]];
      float z[3];
      q3eval<3>(x0, x1, x2, Tl + k * 81, z);
      h[kk][0] += z[0]; h[kk][1] += z[1]; h[kk][2] += z[2];
      wrb[b * STRIDE + 3 * k + 0] = h[kk][0];
      wrb[b * STRIDE + 3 * k + 1] = h[kk][1];
      wrb[b * STRIDE + 3 * k + 2] = h[kk][2];
    }
    __syncthreads();
  }

  // layer 5 (reduce): natural block order = own registers; wire 0 only
  float zv[2];
#pragma unroll
  for (int kk = 0; kk < 2; ++kk) {
    int k = ks + 16 * kk;
    float z[1];
    q3eval<1>(h[kk][0], h[kk][1], h[kk][2], T + (size_t)(5 * 32 + k) * 81, z);
    zv[kk] = z[0];
  }
  // buf[0] was the read buffer of layer 4; barrier above makes it free
  buf[0][b][ks] = zv[0];
  buf[0][b][ks + 16] = zv[1];
  __syncthreads();

  // classifier: out[b][c] = sum_k z[b][k] * wcls[c][k] + bcls[c]
  if (t < NBATCH * 10) {
    int bb = t / 10, c = t % 10;
    float acc = bcls[c];
#pragma unroll
    for (int k = 0; k < 32; ++k)
      acc = fmaf(buf[0][bb][k], wcls[c * 32 + k], acc);
    out[(size_t)(b0 + bb) * 10 + c] = acc;
  }
}

extern "C" void kernel_launch(void* const* d_in, const int* in_sizes, int n_in,
                              void* d_out, int out_size, void* d_ws, size_t ws_size,
                              hipStream_t stream) {
  const float* x  = (const float*)d_in[0];   // (65536, 96) f32
  const float* th = (const float*)d_in[1];   // (6,32,6,3,3) f32
  const float* wc = (const float*)d_in[2];   // (10,32) f32
  const float* bc = (const float*)d_in[3];   // (10,) f32
  float* out = (float*)d_out;                // (65536,10) f32
  float* T = (float*)d_ws;                   // 6*32*3*27 = 15552 floats (62 KB)

  build_T<<<6, 256, 0, stream>>>(th, T);
  vqc_main<<<65536 / NBATCH, 1024, 0, stream>>>(x, T, wc, bc, out);
}

// Round 3
// 56.610 us; speedup vs baseline: 1.2567x; 1.2567x over previous
//
#include <hip/hip_runtime.h>

// ResNetVQC: 6 q3-layers of 32 three-qubit circuits + linear head.
// Each (layer,block,wire) expectation is an exact trilinear form:
//   z_w = sum_{p,q,r} T[w][q][r][p] * v0[p]*v1[q]*v2[r],  v = (1, cos x, sin x)
// T (6*32*3*27 floats) depends only on thetas -> built by a tiny setup kernel.
// Main kernel: 512 threads = 8 waves; lane = batch elem (64/block); each thread
// owns 4 k-blocks (k = ws*4 + kk). Single LDS buffer, read-all/barrier/write.

#define STRIDE 97

// ---------------- setup kernel: build T from thetas ----------------
// grid: 6 blocks (one per q3-layer), 256 threads: k = t>>3 (32 blocks), col = t&7
__global__ __launch_bounds__(256) void build_T(const float* __restrict__ thetas,
                                               float* __restrict__ T) {
  __shared__ float Ur[32][8][8];  // [k][col][amp]
  __shared__ float Ui[32][8][8];
  const int l = blockIdx.x;
  const int t = threadIdx.x;
  const int k = t >> 3;
  const int col = t & 7;

  float pr[8], pi[8];
#pragma unroll
  for (int j = 0; j < 8; ++j) { pr[j] = (j == col) ? 1.f : 0.f; pi[j] = 0.f; }

  const float* th = thetas + (size_t)(l * 32 + k) * 54;  // [d][w][3]
#pragma unroll
  for (int d = 0; d < 6; ++d) {
#pragma unroll
    for (int w = 0; w < 3; ++w) {
      float phi = th[(d * 3 + w) * 3 + 0];
      float tht = th[(d * 3 + w) * 3 + 1];
      float omg = th[(d * 3 + w) * 3 + 2];
      float st, ct, sp, cp, sm, cm;
      __sincosf(0.5f * tht, &st, &ct);
      __sincosf(0.5f * (phi + omg), &sp, &cp);
      __sincosf(0.5f * (phi - omg), &sm, &cm);
      float m00r =  cp * ct, m00i = -sp * ct;
      float m01r = -cm * st, m01i = -sm * st;
      float m10r =  cm * st, m10i = -sm * st;
      float m11r =  cp * ct, m11i =  sp * ct;
      const int s = 4 >> w;  // qubit0 = MSB
#pragma unroll
      for (int base = 0; base < 8; ++base) {
        if (base & s) continue;
        float ar = pr[base], ai = pi[base];
        float br = pr[base + s], bi = pi[base + s];
        pr[base]     = m00r * ar - m00i * ai + m01r * br - m01i * bi;
        pi[base]     = m00r * ai + m00i * ar + m01r * bi + m01i * br;
        pr[base + s] = m10r * ar - m10i * ai + m11r * br - m11i * bi;
        pi[base + s] = m10r * ai + m10i * ar + m11r * bi + m11i * br;
      }
    }
    const int r = (d & 1) + 1;  // CNOT ring range: 1,2,1,2,...
#pragma unroll
    for (int w = 0; w < 3; ++w) {
      const int cs = 4 >> w;
      const int ts = 4 >> ((w + r) % 3);
#pragma unroll
      for (int idx = 0; idx < 8; ++idx) {
        if (!(idx & cs) || (idx & ts)) continue;
        const int j2 = idx | ts;
        float tr = pr[idx]; pr[idx] = pr[j2]; pr[j2] = tr;
        float ti = pi[idx]; pi[idx] = pi[j2]; pi[j2] = ti;
      }
    }
  }
#pragma unroll
  for (int j = 0; j < 8; ++j) { Ur[k][col][j] = pr[j]; Ui[k][col][j] = pi[j]; }
  __syncthreads();

  if (col < 3) {
    const int w = col;  // wire
    float rem[8][8];
#pragma unroll
    for (int a = 0; a < 8; ++a) {
#pragma unroll
      for (int bb = 0; bb < 8; ++bb) {
        float acc = 0.f;
#pragma unroll
        for (int c = 0; c < 8; ++c) {
          float zs = ((c >> (2 - w)) & 1) ? -1.f : 1.f;
          acc += zs * (Ur[k][a][c] * Ur[k][bb][c] + Ui[k][a][c] * Ui[k][bb][c]);
        }
        rem[a][bb] = acc;
      }
    }
    const int   ga[3][2] = {{0, 1}, {0, 1}, {0, 1}};
    const int   gb[3][2] = {{0, 1}, {0, 1}, {1, 0}};
    const float gc[3][2] = {{0.5f, 0.5f}, {0.5f, -0.5f}, {0.5f, 0.5f}};
    float* To = T + ((size_t)(l * 32 + k) * 3 + w) * 27;
#pragma unroll
    for (int p = 0; p < 3; ++p) {
#pragma unroll
      for (int q = 0; q < 3; ++q) {
#pragma unroll
        for (int rr = 0; rr < 3; ++rr) {
          float acc = 0.f;
#pragma unroll
          for (int e0 = 0; e0 < 2; ++e0)
#pragma unroll
            for (int e1 = 0; e1 < 2; ++e1)
#pragma unroll
              for (int e2 = 0; e2 < 2; ++e2) {
                int a  = (ga[p][e0] << 2) | (ga[q][e1] << 1) | ga[rr][e2];
                int bb = (gb[p][e0] << 2) | (gb[q][e1] << 1) | gb[rr][e2];
                acc += gc[p][e0] * gc[q][e1] * gc[rr][e2] * rem[a][bb];
              }
          To[q * 9 + rr * 3 + p] = acc;  // layout [w][q][r][p]
        }
      }
    }
  }
}

// ---------------- main kernel ----------------
// Nested-Horner trilinear contraction: 26 FMA per wire, 6-deep chains.
template <int NW>
__device__ __forceinline__ void q3eval(float x0, float x1, float x2,
                                       const float* __restrict__ tb,
                                       float* __restrict__ zz) {
  float s0, c0, s1, c1, s2, c2;
  __sincosf(x0, &s0, &c0);
  __sincosf(x1, &s1, &c1);
  __sincosf(x2, &s2, &c2);
#pragma unroll
  for (int w = 0; w < NW; ++w) {
    const float* tt = tb + w * 27;
    float Bv[3];
#pragma unroll
    for (int r = 0; r < 3; ++r) {
      float a0 = fmaf(s0, tt[0 * 9 + r * 3 + 2], fmaf(c0, tt[0 * 9 + r * 3 + 1], tt[0 * 9 + r * 3 + 0]));
      float a1 = fmaf(s0, tt[1 * 9 + r * 3 + 2], fmaf(c0, tt[1 * 9 + r * 3 + 1], tt[1 * 9 + r * 3 + 0]));
      float a2 = fmaf(s0, tt[2 * 9 + r * 3 + 2], fmaf(c0, tt[2 * 9 + r * 3 + 1], tt[2 * 9 + r * 3 + 0]));
      Bv[r] = fmaf(s1, a2, fmaf(c1, a1, a0));
    }
    zz[w] = fmaf(s2, Bv[2], fmaf(c2, Bv[1], Bv[0]));
  }
}

// block = 512 threads = 8 waves; lane b = batch elem (64/block); wave ws owns
// k-blocks {4ws .. 4ws+3}. One LDS buffer [64][97]; read-all -> B -> write -> B.
__global__ __launch_bounds__(512, 8) void vqc_main(const float* __restrict__ x,
                                                   const float* __restrict__ T,
                                                   const float* __restrict__ wcls,
                                                   const float* __restrict__ bcls,
                                                   float* __restrict__ out) {
  __shared__ float buf[64 * STRIDE];  // 24832 B
  const int t = threadIdx.x;
  const int b0 = blockIdx.x * 64;

  // stage x (coalesced float4 reads) into buf
  const float4* xv = (const float4*)(x + (size_t)b0 * 96);
#pragma unroll
  for (int i = 0; i < 3; ++i) {
    float4 v = xv[t + i * 512];
    int idx = (t + i * 512) * 4;
    int row = idx / 96, col = idx % 96;
    float* p = &buf[row * STRIDE + col];
    p[0] = v.x; p[1] = v.y; p[2] = v.z; p[3] = v.w;
  }

  const int b = t & 63;                                   // batch within block
  const int ws = __builtin_amdgcn_readfirstlane(t >> 6);  // wave id 0..7 (scalar)

  // "fully" permutation gather indices: inp[3k+j] = H[3*((3k+j)%32) + (3k+j)/32]
  int gf[4][3];
#pragma unroll
  for (int kk = 0; kk < 4; ++kk) {
    int k = ws * 4 + kk;
#pragma unroll
    for (int j = 0; j < 3; ++j) {
      int m = 3 * k + j;
      gf[kk][j] = 3 * (m & 31) + (m >> 5);
    }
  }
  __syncthreads();

  float h[4][3];
  // layer 0 (stem): natural block order (own positions), no residual
#pragma unroll
  for (int kk = 0; kk < 4; ++kk) {
    int k = ws * 4 + kk;
    float z[3];
    q3eval<3>(buf[b * STRIDE + 3 * k + 0], buf[b * STRIDE + 3 * k + 1],
              buf[b * STRIDE + 3 * k + 2], T + (size_t)k * 81, z);
#pragma unroll
    for (int j = 0; j < 3; ++j) {
      h[kk][j] = z[j];
      buf[b * STRIDE + 3 * k + j] = z[j];  // own positions: no race
    }
  }
  __syncthreads();

  // layers 1..4: permuted gather, residual add (residual = own regs)
  for (int l = 1; l < 5; ++l) {
    const float* Tl = T + (size_t)l * 32 * 81;
    float xin[4][3];
#pragma unroll
    for (int kk = 0; kk < 4; ++kk)
#pragma unroll
      for (int j = 0; j < 3; ++j) xin[kk][j] = buf[b * STRIDE + gf[kk][j]];
    __syncthreads();  // all reads of H_{l-1} done
#pragma unroll
    for (int kk = 0; kk < 4; ++kk) {
      int k = ws * 4 + kk;
      float z[3];
      q3eval<3>(xin[kk][0], xin[kk][1], xin[kk][2], Tl + k * 81, z);
#pragma unroll
      for (int j = 0; j < 3; ++j) h[kk][j] += z[j];
      if (l < 4) {
#pragma unroll
        for (int j = 0; j < 3; ++j) buf[b * STRIDE + 3 * k + j] = h[kk][j];
      }
    }
    if (l < 4) __syncthreads();  // writes of H_l visible before next gathers
  }

  // layer 5 (reduce): input = own registers; wire 0 only; stash z into buf[b][k]
#pragma unroll
  for (int kk = 0; kk < 4; ++kk) {
    int k = ws * 4 + kk;
    float z[1];
    q3eval<1>(h[kk][0], h[kk][1], h[kk][2], T + (size_t)(5 * 32 + k) * 81, z);
    buf[b * STRIDE + k] = z[0];  // safe: layer-4 gathers completed at last barrier
  }
  __syncthreads();

  // classifier: out[b][c] = sum_k z[b][k] * wcls[c][k] + bcls[c]
  // 640 work items on 512 threads -> grid-stride (t<128 do two)
  for (int idx = t; idx < 640; idx += 512) {
    int bb = idx / 10, c = idx % 10;
    float acc = bcls[c];
#pragma unroll
    for (int k = 0; k < 32; ++k)
      acc = fmaf(buf[bb * STRIDE + k], wcls[c * 32 + k], acc);
    out[(size_t)(b0 + bb) * 10 + c] = acc;
  }
}

extern "C" void kernel_launch(void* const* d_in, const int* in_sizes, int n_in,
                              void* d_out, int out_size, void* d_ws, size_t ws_size,
                              hipStream_t stream) {
  const float* x  = (const float*)d_in[0];   // (65536, 96) f32
  const float* th = (const float*)d_in[1];   // (6,32,6,3,3) f32
  const float* wc = (const float*)d_in[2];   // (10,32) f32
  const float* bc = (const float*)d_in[3];   // (10,) f32
  float* out = (float*)d_out;                // (65536,10) f32
  float* T = (float*)d_ws;                   // 6*32*81 = 15552 floats (62 KB)

  build_T<<<6, 256, 0, stream>>>(th, T);
  vqc_main<<<65536 / 64, 512, 0, stream>>>(x, T, wc, bc, out);
}